// Round 1
// baseline (206.656 us; speedup 1.0000x reference)
//
#include <hip/hip_runtime.h>

constexpr int B = 8, H = 512, W = 512;
constexpr int PLANE = H * W;              // 262144
constexpr int NPIX  = B * PLANE;          // 2097152  (pixels per channel-plane across batch)
constexpr int BSTRIDE = 2 * PLANE;        // batch stride (2 channels)
constexpr int UPN = B * 1024 * 1024;      // 8388608 upsampled pixels

__device__ __forceinline__ float reluf(float v) { return v > 0.f ? v : 0.f; }

// One thread per (b, y, x); handles both channels.
// Computes: attn_conv(input) [+ res0] [+ res1]
template<int NRES>
__global__ __launch_bounds__(256) void attn_kernel(
    const float* __restrict__ x,
    const float* __restrict__ r0,
    const float* __restrict__ r1,
    float* __restrict__ out,
    const float* __restrict__ wq, const float* __restrict__ bq,
    const float* __restrict__ wk, const float* __restrict__ bk,
    const float* __restrict__ wv, const float* __restrict__ bv,
    const float* __restrict__ rh, const float* __restrict__ rw)
{
    int p  = blockIdx.x * 256 + threadIdx.x;   // grid sized exactly NPIX/256
    int b  = p >> 18;
    int y  = (p >> 9) & 511;
    int xx = p & 511;

    // uniform weights (scalar-cached)
    float wq00 = wq[0], wq01 = wq[1], wq10 = wq[2], wq11 = wq[3];
    float bq0 = bq[0], bq1 = bq[1];
    float wk00 = wk[0], wk01 = wk[1], wk10 = wk[2], wk11 = wk[3];
    float bk0 = bk[0], bk1 = bk[1];
    float wv00 = wv[0], wv01 = wv[1], wv10 = wv[2], wv11 = wv[3];
    float bv0 = bv[0], bv1 = bv[1];
    float rh0 = rh[0], rh1 = rh[1], rh2 = rh[2];
    float rw0 = rw[0], rw1 = rw[1], rw2 = rw[2];
    float rhv[3] = {rh0, rh1, rh2};
    float rwv[3] = {rw0, rw1, rw2};

    int base0 = b * BSTRIDE + y * W + xx;
    int base1 = base0 + PLANE;

    float c0 = reluf(x[base0]);
    float c1 = reluf(x[base1]);
    float q0 = wq00 * c0 + wq01 * c1 + bq0;
    float q1 = wq10 * c0 + wq11 * c1 + bq1;

    float s0[9], s1[9], v0a[9], v1a[9];
#pragma unroll
    for (int dy = -1; dy <= 1; ++dy) {
#pragma unroll
        for (int dx = -1; dx <= 1; ++dx) {
            int t = (dy + 1) * 3 + (dx + 1);
            int yy = y + dy, xn = xx + dx;
            float n0 = 0.f, n1 = 0.f;
            if (yy >= 0 && yy < H && xn >= 0 && xn < W) {
                int o = b * BSTRIDE + yy * W + xn;
                n0 = reluf(x[o]);
                n1 = reluf(x[o + PLANE]);
            }
            // zero-pad happens BEFORE conv1x1: bias + relpos always added
            float k0 = wk00 * n0 + wk01 * n1 + bk0 + rhv[dy + 1];  // ch0: rh by row
            float k1 = wk10 * n0 + wk11 * n1 + bk1 + rwv[dx + 1];  // ch1: rw by col
            v0a[t] = wv00 * n0 + wv01 * n1 + bv0;
            v1a[t] = wv10 * n0 + wv11 * n1 + bv1;
            s0[t] = q0 * k0;
            s1[t] = q1 * k1;
        }
    }

    float m0 = s0[0], m1 = s1[0];
#pragma unroll
    for (int t = 1; t < 9; ++t) { m0 = fmaxf(m0, s0[t]); m1 = fmaxf(m1, s1[t]); }
    float sum0 = 0.f, acc0 = 0.f, sum1 = 0.f, acc1 = 0.f;
#pragma unroll
    for (int t = 0; t < 9; ++t) {
        float e0 = __expf(s0[t] - m0);
        float e1 = __expf(s1[t] - m1);
        sum0 += e0; acc0 += e0 * v0a[t];
        sum1 += e1; acc1 += e1 * v1a[t];
    }
    float o0 = acc0 / sum0;
    float o1 = acc1 / sum1;

    if (NRES >= 1) { o0 += r0[base0]; o1 += r0[base1]; }
    if (NRES >= 2) { o0 += r1[base0]; o1 += r1[base1]; }

    out[base0] = o0;
    out[base1] = o1;
}

// reflect-pad 3x3 conv (2ch -> 1ch) + sigmoid
__global__ __launch_bounds__(256) void conv_sig_kernel(
    const float* __restrict__ u,
    const float* __restrict__ cw, const float* __restrict__ cb,
    float* __restrict__ o)
{
    int p  = blockIdx.x * 256 + threadIdx.x;
    int b  = p >> 18;
    int y  = (p >> 9) & 511;
    int xx = p & 511;

    float w[18];
#pragma unroll
    for (int i = 0; i < 18; ++i) w[i] = cw[i];
    float acc = cb[0];

#pragma unroll
    for (int c = 0; c < 2; ++c) {
        const float* up = u + b * BSTRIDE + c * PLANE;
#pragma unroll
        for (int i = 0; i < 3; ++i) {
            int yy = y + i - 1;
            if (yy < 0) yy = -yy;            // reflect (-1 -> 1)
            if (yy > H - 1) yy = 2 * (H - 1) - yy;  // (512 -> 510)
#pragma unroll
            for (int j = 0; j < 3; ++j) {
                int xn = xx + j - 1;
                if (xn < 0) xn = -xn;
                if (xn > W - 1) xn = 2 * (W - 1) - xn;
                acc += up[yy * W + xn] * w[c * 9 + i * 3 + j];
            }
        }
    }
    o[p] = 1.f / (1.f + __expf(-acc));
}

// 2x bilinear upsample, align-corners-style grid: ys = linspace(0, 511, 1024)
__global__ __launch_bounds__(256) void upsample_kernel(
    const float* __restrict__ o, float* __restrict__ up)
{
    int p  = blockIdx.x * 256 + threadIdx.x;
    int b  = p >> 20;
    int y  = (p >> 10) & 1023;
    int xx = p & 1023;

    const float scale = 511.0f / 1023.0f;
    float fy = y * scale;
    float fx = xx * scale;
    int y0 = (int)fy, x0 = (int)fx;
    float wy = fy - y0, wx = fx - x0;
    int y1 = min(y0 + 1, H - 1);
    int x1 = min(x0 + 1, W - 1);

    const float* ob = o + b * PLANE;
    float v00 = ob[y0 * W + x0];
    float v01 = ob[y0 * W + x1];
    float v10 = ob[y1 * W + x0];
    float v11 = ob[y1 * W + x1];

    up[p] = v00 * (1.f - wy) * (1.f - wx) + v01 * (1.f - wy) * wx
          + v10 * wy * (1.f - wx) + v11 * wy * wx;
}

extern "C" void kernel_launch(void* const* d_in, const int* in_sizes, int n_in,
                              void* d_out, int out_size, void* d_ws, size_t ws_size,
                              hipStream_t stream) {
    const float* in1 = (const float*)d_in[0];
    const float* in2 = (const float*)d_in[1];
    const float* wq  = (const float*)d_in[2];
    const float* bq  = (const float*)d_in[3];
    const float* wk  = (const float*)d_in[4];
    const float* bk  = (const float*)d_in[5];
    const float* wv  = (const float*)d_in[6];
    const float* bv  = (const float*)d_in[7];
    const float* rh  = (const float*)d_in[8];
    const float* rw  = (const float*)d_in[9];
    const float* cw  = (const float*)d_in[10];
    const float* cb  = (const float*)d_in[11];

    float* out = (float*)d_out;

    // Buffer plan (each tensor = 4,194,304 floats = 16 MB):
    //   bufA = d_ws[0 : 16MB]
    //   bufB = d_out[4194304 : 8388608]   (final writes happen only in last 2 kernels)
    //   bufC = d_out[0 : 4194304]
    float* bufA = (float*)d_ws;
    float* bufB = out + 4194304;
    float* bufC = out;

    const int TENS = 4194304;  // elements per full tensor (unused, doc)
    (void)TENS; (void)ws_size; (void)out_size; (void)n_in; (void)in_sizes;

    dim3 blk(256);
    int gridN = NPIX / 256;    // 8192
    int gridU = UPN / 256;     // 32768

    // rau(input_1, u=0): params 0,1
    attn_kernel<0><<<gridN, blk, 0, stream>>>(in1, nullptr, nullptr, bufA,
        wq + 0, bq + 0, wk + 0, bk + 0, wv + 0, bv + 0, rh + 0, rw + 0);
    // t2 = attn(relu(t1), p1) + in1   -> bufB
    attn_kernel<1><<<gridN, blk, 0, stream>>>(bufA, in1, nullptr, bufB,
        wq + 4, bq + 2, wk + 4, bk + 2, wv + 4, bv + 2, rh + 3, rw + 3);
    // rau(input_2, u=1): params 2,3
    attn_kernel<0><<<gridN, blk, 0, stream>>>(in2, nullptr, nullptr, bufA,
        wq + 8, bq + 4, wk + 8, bk + 4, wv + 8, bv + 4, rh + 6, rw + 6);
    // s = attn(relu(t3), p3) + in2 + t2   -> bufC   (== rau0_out + rau1_out)
    attn_kernel<2><<<gridN, blk, 0, stream>>>(bufA, in2, bufB, bufC,
        wq + 12, bq + 6, wk + 12, bk + 6, wv + 12, bv + 6, rh + 9, rw + 9);
    // rau(s, u=2): params 4,5
    attn_kernel<0><<<gridN, blk, 0, stream>>>(bufC, nullptr, nullptr, bufA,
        wq + 16, bq + 8, wk + 16, bk + 8, wv + 16, bv + 8, rh + 12, rw + 12);
    // u = attn(relu(t5), p5) + s   -> bufB
    attn_kernel<1><<<gridN, blk, 0, stream>>>(bufA, bufC, nullptr, bufB,
        wq + 20, bq + 10, wk + 20, bk + 10, wv + 20, bv + 10, rh + 15, rw + 15);
    // o = sigmoid(conv3x3(reflect_pad(u)))  -> d_out[0 : 2097152]
    conv_sig_kernel<<<gridN, blk, 0, stream>>>(bufB, cw, cb, out);
    // up = bilinear2x(o)  -> d_out[2097152 : 10485760]
    upsample_kernel<<<gridU, blk, 0, stream>>>(out, out + NPIX);
}

// Round 2
// 139.103 us; speedup vs baseline: 1.4856x; 1.4856x over previous
//
#include <hip/hip_runtime.h>

constexpr int B = 8, H = 512, W = 512;
constexpr int PLANE = H * W;              // 262144
constexpr int NPIX  = B * PLANE;          // 2097152 pixels (per 2-ch image set)
constexpr int BSTRIDE = 2 * PLANE;
constexpr int UPN = B * 1024 * 1024;      // 8388608 upsampled pixels
constexpr float LOG2E = 1.4426950408889634f;

__device__ __forceinline__ float reluf(float v) { return v > 0.f ? v : 0.f; }
__device__ __forceinline__ float frcp(float v) { return __builtin_amdgcn_rcpf(v); }

// Each thread computes a 1x4 strip of output pixels, both channels.
// attn_conv(relu(x)) [+ r0] [+ r1]
template<int NRES>
__global__ __launch_bounds__(256) void attn4_kernel(
    const float* __restrict__ x,
    const float* __restrict__ r0,
    const float* __restrict__ r1,
    float* __restrict__ out,
    const float* __restrict__ wq, const float* __restrict__ bq,
    const float* __restrict__ wk, const float* __restrict__ bk,
    const float* __restrict__ wv, const float* __restrict__ bv,
    const float* __restrict__ rh, const float* __restrict__ rw)
{
    int s  = blockIdx.x * 256 + threadIdx.x;     // strip id, 524288 total
    int xq = (s & 127) * 4;
    int y  = (s >> 7) & 511;
    int b  = s >> 16;

    // uniform params -> SGPRs
    float wq00 = wq[0], wq01 = wq[1], wq10 = wq[2], wq11 = wq[3];
    float bq0 = bq[0], bq1 = bq[1];
    float wk00 = wk[0], wk01 = wk[1], wk10 = wk[2], wk11 = wk[3];
    float bk0 = bk[0], bk1 = bk[1];
    float wv00 = wv[0], wv01 = wv[1], wv10 = wv[2], wv11 = wv[3];
    float bv0 = bv[0], bv1 = bv[1];
    float rhv[3] = {rh[0], rh[1], rh[2]};
    float rwv[3] = {rw[0], rw[1], rw[2]};

    const float* xb = x + b * BSTRIDE;
    bool rowv[3] = { y > 0, true, y < H - 1 };
    int  yr[3]   = { y > 0 ? y - 1 : 0, y, y < H - 1 ? y + 1 : H - 1 };
    bool lv   = xq > 0;
    bool rvld = xq < W - 4;
    int  xl = lv ? xq - 1 : 0;
    int  xr = rvld ? xq + 4 : W - 1;

    // per-location k-base (bias folded, rel-pos NOT folded) and v, shared by the 4 pixels
    float kb0[3][6], kb1[3][6], v0[3][6], v1[3][6];
    float cc0[4], cc1[4];   // relu'd centers

#pragma unroll
    for (int r = 0; r < 3; ++r) {
        const float* p0 = xb + yr[r] * W;
        const float* p1 = p0 + PLANE;
        float4 a0 = *reinterpret_cast<const float4*>(p0 + xq);
        float4 a1 = *reinterpret_cast<const float4*>(p1 + xq);
        float t0[6] = { p0[xl], a0.x, a0.y, a0.z, a0.w, p0[xr] };
        float t1[6] = { p1[xl], a1.x, a1.y, a1.z, a1.w, p1[xr] };
        bool rv_ = rowv[r];
#pragma unroll
        for (int c = 0; c < 6; ++c) {
            bool ok = rv_ && (c > 0 || lv) && (c < 5 || rvld);
            float u0 = ok ? reluf(t0[c]) : 0.f;
            float u1 = ok ? reluf(t1[c]) : 0.f;
            kb0[r][c] = fmaf(wk00, u0, fmaf(wk01, u1, bk0));
            kb1[r][c] = fmaf(wk10, u0, fmaf(wk11, u1, bk1));
            v0[r][c]  = fmaf(wv00, u0, fmaf(wv01, u1, bv0));
            v1[r][c]  = fmaf(wv10, u0, fmaf(wv11, u1, bv1));
            if (r == 1 && c >= 1 && c <= 4) { cc0[c - 1] = u0; cc1[c - 1] = u1; }
        }
    }

    float out0[4], out1[4];
#pragma unroll
    for (int px = 0; px < 4; ++px) {
        float c0 = cc0[px], c1 = cc1[px];
        float q0 = fmaf(wq00, c0, fmaf(wq01, c1, bq0)) * LOG2E;
        float q1 = fmaf(wq10, c0, fmaf(wq11, c1, bq1)) * LOG2E;
        float qh[3] = { q0 * rhv[0], q0 * rhv[1], q0 * rhv[2] };  // ch0: rh by row
        float qw[3] = { q1 * rwv[0], q1 * rwv[1], q1 * rwv[2] };  // ch1: rw by col
        float s0[9], s1[9];
#pragma unroll
        for (int r = 0; r < 3; ++r)
#pragma unroll
            for (int d = 0; d < 3; ++d) {
                s0[r * 3 + d] = fmaf(q0, kb0[r][px + d], qh[r]);
                s1[r * 3 + d] = fmaf(q1, kb1[r][px + d], qw[d]);
            }
        float m0 = fmaxf(fmaxf(fmaxf(fmaxf(s0[0], s0[1]), fmaxf(s0[2], s0[3])),
                               fmaxf(fmaxf(s0[4], s0[5]), fmaxf(s0[6], s0[7]))), s0[8]);
        float m1 = fmaxf(fmaxf(fmaxf(fmaxf(s1[0], s1[1]), fmaxf(s1[2], s1[3])),
                               fmaxf(fmaxf(s1[4], s1[5]), fmaxf(s1[6], s1[7]))), s1[8]);
        float sum0 = 0.f, acc0 = 0.f, sum1 = 0.f, acc1 = 0.f;
#pragma unroll
        for (int r = 0; r < 3; ++r)
#pragma unroll
            for (int d = 0; d < 3; ++d) {
                int t = r * 3 + d;
                float e0 = exp2f(s0[t] - m0);
                float e1 = exp2f(s1[t] - m1);
                sum0 += e0; acc0 = fmaf(e0, v0[r][px + d], acc0);
                sum1 += e1; acc1 = fmaf(e1, v1[r][px + d], acc1);
            }
        out0[px] = acc0 * frcp(sum0);
        out1[px] = acc1 * frcp(sum1);
    }

    int base0 = b * BSTRIDE + y * W + xq;
    int base1 = base0 + PLANE;
    if (NRES >= 1) {
        float4 ra = *reinterpret_cast<const float4*>(r0 + base0);
        float4 rb = *reinterpret_cast<const float4*>(r0 + base1);
        out0[0] += ra.x; out0[1] += ra.y; out0[2] += ra.z; out0[3] += ra.w;
        out1[0] += rb.x; out1[1] += rb.y; out1[2] += rb.z; out1[3] += rb.w;
    }
    if (NRES >= 2) {
        float4 ra = *reinterpret_cast<const float4*>(r1 + base0);
        float4 rb = *reinterpret_cast<const float4*>(r1 + base1);
        out0[0] += ra.x; out0[1] += ra.y; out0[2] += ra.z; out0[3] += ra.w;
        out1[0] += rb.x; out1[1] += rb.y; out1[2] += rb.z; out1[3] += rb.w;
    }
    *reinterpret_cast<float4*>(out + base0) = make_float4(out0[0], out0[1], out0[2], out0[3]);
    *reinterpret_cast<float4*>(out + base1) = make_float4(out1[0], out1[1], out1[2], out1[3]);
}

// reflect-pad 3x3 conv (2ch -> 1ch) + sigmoid, 4 px per thread
__global__ __launch_bounds__(256) void conv_sig4_kernel(
    const float* __restrict__ u,
    const float* __restrict__ cw, const float* __restrict__ cb,
    float* __restrict__ o)
{
    int s  = blockIdx.x * 256 + threadIdx.x;
    int x0 = (s & 127) * 4;
    int y  = (s >> 7) & 511;
    int b  = s >> 16;

    float w[18];
#pragma unroll
    for (int i = 0; i < 18; ++i) w[i] = cw[i];

    int yy[3];
#pragma unroll
    for (int i = 0; i < 3; ++i) {
        int t = y + i - 1;
        if (t < 0) t = -t;
        if (t > H - 1) t = 2 * (H - 1) - t;
        yy[i] = t;
    }
    int xl = x0 - 1; if (xl < 0) xl = 1;
    int xr = x0 + 4; if (xr > W - 1) xr = 2 * (W - 1) - xr;

    float acc[4] = { cb[0], cb[0], cb[0], cb[0] };
#pragma unroll
    for (int c = 0; c < 2; ++c) {
        const float* up = u + b * BSTRIDE + c * PLANE;
#pragma unroll
        for (int i = 0; i < 3; ++i) {
            const float* row = up + yy[i] * W;
            float4 a = *reinterpret_cast<const float4*>(row + x0);
            float t[6] = { row[xl], a.x, a.y, a.z, a.w, row[xr] };
#pragma unroll
            for (int j = 0; j < 3; ++j) {
                float wc = w[c * 9 + i * 3 + j];
#pragma unroll
                for (int px = 0; px < 4; ++px)
                    acc[px] = fmaf(t[px + j], wc, acc[px]);
            }
        }
    }
    float4 ov;
    ov.x = frcp(1.f + exp2f(-acc[0] * LOG2E));
    ov.y = frcp(1.f + exp2f(-acc[1] * LOG2E));
    ov.z = frcp(1.f + exp2f(-acc[2] * LOG2E));
    ov.w = frcp(1.f + exp2f(-acc[3] * LOG2E));
    *reinterpret_cast<float4*>(o + b * PLANE + y * W + x0) = ov;
}

// 2x bilinear upsample (linspace(0,511,1024) grid), 4 out px per thread
__global__ __launch_bounds__(256) void upsample4_kernel(
    const float* __restrict__ o, float* __restrict__ up)
{
    int p  = blockIdx.x * 256 + threadIdx.x;   // 2097152 strips
    int b  = p >> 18;
    int y  = (p >> 8) & 1023;
    int x0 = (p & 255) * 4;

    const float scale = 511.0f / 1023.0f;
    float fy = y * scale;
    int y0 = (int)fy;
    float wy = fy - y0;
    int y1 = min(y0 + 1, H - 1);

    const float* ob = o + b * PLANE;
    const float* row0 = ob + y0 * W;
    const float* row1 = ob + y1 * W;

    float4 ov;
    float* ovp = &ov.x;
#pragma unroll
    for (int j = 0; j < 4; ++j) {
        float fx = (x0 + j) * scale;
        int xi = (int)fx;
        float wx = fx - xi;
        int xi1 = min(xi + 1, W - 1);
        float v00 = row0[xi], v01 = row0[xi1];
        float v10 = row1[xi], v11 = row1[xi1];
        float top = fmaf(v01 - v00, wx, v00);
        float bot = fmaf(v11 - v10, wx, v10);
        ovp[j] = fmaf(bot - top, wy, top);
    }
    *reinterpret_cast<float4*>(up + ((long)b << 20) + y * 1024 + x0) = ov;
}

extern "C" void kernel_launch(void* const* d_in, const int* in_sizes, int n_in,
                              void* d_out, int out_size, void* d_ws, size_t ws_size,
                              hipStream_t stream) {
    const float* in1 = (const float*)d_in[0];
    const float* in2 = (const float*)d_in[1];
    const float* wq  = (const float*)d_in[2];
    const float* bq  = (const float*)d_in[3];
    const float* wk  = (const float*)d_in[4];
    const float* bk  = (const float*)d_in[5];
    const float* wv  = (const float*)d_in[6];
    const float* bv  = (const float*)d_in[7];
    const float* rh  = (const float*)d_in[8];
    const float* rw  = (const float*)d_in[9];
    const float* cw  = (const float*)d_in[10];
    const float* cb  = (const float*)d_in[11];

    float* out = (float*)d_out;

    // bufA = ws; bufB/bufC alias d_out (finals only written by last 2 kernels)
    float* bufA = (float*)d_ws;
    float* bufB = out + 4194304;
    float* bufC = out;
    (void)ws_size; (void)out_size; (void)n_in; (void)in_sizes;

    dim3 blk(256);
    int gridA = (NPIX / 4) / 256;   // 2048
    int gridU = (UPN / 4) / 256;    // 8192

    attn4_kernel<0><<<gridA, blk, 0, stream>>>(in1, nullptr, nullptr, bufA,
        wq + 0, bq + 0, wk + 0, bk + 0, wv + 0, bv + 0, rh + 0, rw + 0);
    attn4_kernel<1><<<gridA, blk, 0, stream>>>(bufA, in1, nullptr, bufB,
        wq + 4, bq + 2, wk + 4, bk + 2, wv + 4, bv + 2, rh + 3, rw + 3);
    attn4_kernel<0><<<gridA, blk, 0, stream>>>(in2, nullptr, nullptr, bufA,
        wq + 8, bq + 4, wk + 8, bk + 4, wv + 8, bv + 4, rh + 6, rw + 6);
    attn4_kernel<2><<<gridA, blk, 0, stream>>>(bufA, in2, bufB, bufC,
        wq + 12, bq + 6, wk + 12, bk + 6, wv + 12, bv + 6, rh + 9, rw + 9);
    attn4_kernel<0><<<gridA, blk, 0, stream>>>(bufC, nullptr, nullptr, bufA,
        wq + 16, bq + 8, wk + 16, bk + 8, wv + 16, bv + 8, rh + 12, rw + 12);
    attn4_kernel<1><<<gridA, blk, 0, stream>>>(bufA, bufC, nullptr, bufB,
        wq + 20, bq + 10, wk + 20, bk + 10, wv + 20, bv + 10, rh + 15, rw + 15);
    conv_sig4_kernel<<<gridA, blk, 0, stream>>>(bufB, cw, cb, out);
    upsample4_kernel<<<gridU, blk, 0, stream>>>(out, out + NPIX);
}